// Round 1
// baseline (2774.736 us; speedup 1.0000x reference)
//
#include <hip/hip_runtime.h>

// Problem constants (B, L, C, H, O) = (4096, 256, 16, 128, 4)
#define NB 4096
#define NL 256
#define NC 16
#define NH 128
#define NO 4

// Broadcast a wave-uniform-by-construction value from lane `l` (compile-time
// constant after unroll) -> lands in an SGPR, usable as the scalar operand of
// v_fma.
__device__ __forceinline__ float lane_bcast(float v, int l) {
  return __uint_as_float(__builtin_amdgcn_readlane(__float_as_uint(v), l));
}

__device__ __forceinline__ float fast_exp2(float x) {
#if __has_builtin(__builtin_amdgcn_exp2f)
  return __builtin_amdgcn_exp2f(x);
#else
  return exp2f(x);
#endif
}

__device__ __forceinline__ float fast_rcp(float x) {
#if __has_builtin(__builtin_amdgcn_rcpf)
  return __builtin_amdgcn_rcpf(x);
#else
  return 1.0f / x;
#endif
}

// tanh(x) = 1 - 2/(exp(2x)+1) ; exp(2x) = exp2(2*log2(e)*x)
// Saturates correctly for |x| large (inf -> 1, 0 -> -1). ~1e-6 abs error.
__device__ __forceinline__ float tanh_fast(float x) {
  float e = fast_exp2(x * 2.88539008177792681472f);
  return fmaf(-2.0f, fast_rcp(e + 1.0f), 1.0f);
}

__global__ __launch_bounds__(256) void ncde_kernel(
    const float* __restrict__ coeffs,  // (B, L-1, 4*C)
    const float* __restrict__ W_init,  // (C, H)
    const float* __restrict__ b_init,  // (H,)
    const float* __restrict__ W1,      // (H, 2)
    const float* __restrict__ b1,      // (2,)
    const float* __restrict__ W2,      // (2, H*C)
    const float* __restrict__ b2,      // (H*C,)
    const float* __restrict__ W_out,   // (H, O)
    const float* __restrict__ b_out,   // (O,)
    float* __restrict__ out)           // (B, L, O)
{
  const int lane = threadIdx.x & 63;
  const int wid  = threadIdx.x >> 6;
  const int bat  = blockIdx.x * 4 + wid;   // one wave per batch element
  const int hA = lane;          // this lane's first h index
  const int hB = lane + 64;     // this lane's second h index

  // ---- Loop-invariant weights in registers ----
  // 32 tanh entries per lane: (hA, c=0..15) then (hB, c=0..15)
  float w2a[32], w2b[32], b2r[32];
#pragma unroll
  for (int c = 0; c < NC; ++c) {
    w2a[c]      = W2[hA * NC + c];              // W2[0][h*16+c]
    w2a[16 + c] = W2[hB * NC + c];
    w2b[c]      = W2[NH * NC + hA * NC + c];    // W2[1][h*16+c]
    w2b[16 + c] = W2[NH * NC + hB * NC + c];
    b2r[c]      = b2[hA * NC + c];
    b2r[16 + c] = b2[hB * NC + c];
  }
  const float w1A0 = W1[hA * 2 + 0], w1A1 = W1[hA * 2 + 1];
  const float w1B0 = W1[hB * 2 + 0], w1B1 = W1[hB * 2 + 1];
  float woA[4], woB[4], bo[4];
#pragma unroll
  for (int o = 0; o < NO; ++o) {
    woA[o] = W_out[hA * NO + o];
    woB[o] = W_out[hB * NO + o];
    bo[o]  = b_out[o];
  }
  const float b1_0 = b1[0], b1_1 = b1[1];

  const float* crow = coeffs + (size_t)bat * (NL - 1) * (4 * NC);
  float* obase = out + (size_t)bat * NL * NO;

  // ---- z0 = X0 @ W_init + b_init ; X0 = coeffs[b, 0, 0:16] ----
  float v0 = crow[lane];  // row 0: lanes 0..15 hold a, 16..31 sb, 32..47 sc, 48..63 sd
  float za = b_init[hA], zb = b_init[hB];
#pragma unroll
  for (int c = 0; c < NC; ++c) {
    float xc = lane_bcast(v0, c);
    za = fmaf(xc, W_init[c * NH + hA], za);
    zb = fmaf(xc, W_init[c * NH + hB], zb);
  }

  // ---- output projection: out[b,t,:] = z @ W_out + b_out ----
  auto store_out = [&](int t, float a_, float b_) {
    float p0 = fmaf(a_, woA[0], b_ * woB[0]);
    float p1 = fmaf(a_, woA[1], b_ * woB[1]);
    float p2 = fmaf(a_, woA[2], b_ * woB[2]);
    float p3 = fmaf(a_, woA[3], b_ * woB[3]);
#pragma unroll
    for (int m = 32; m >= 1; m >>= 1) {
      p0 += __shfl_xor(p0, m, 64);
      p1 += __shfl_xor(p1, m, 64);
      p2 += __shfl_xor(p2, m, 64);
      p3 += __shfl_xor(p3, m, 64);
    }
    if (lane == 0) {
      float4 r;
      r.x = p0 + bo[0]; r.y = p1 + bo[1]; r.z = p2 + bo[2]; r.w = p3 + bo[3];
      *(float4*)(obase + (size_t)t * NO) = r;
    }
  };

  // ---- vf(z, xdot): h = relu(z@W1+b1); g = tanh(h@W2+b2); k = g . xdot ----
  auto vf = [&](float zsa, float zsb, float xd, float& k0, float& k1) {
    // z @ W1 : full-wave butterfly sum (each lane contributes 2 h's)
    float p0 = fmaf(zsa, w1A0, zsb * w1B0);
    float p1 = fmaf(zsa, w1A1, zsb * w1B1);
#pragma unroll
    for (int m = 32; m >= 1; m >>= 1) {
      p0 += __shfl_xor(p0, m, 64);
      p1 += __shfl_xor(p1, m, 64);
    }
    float hh0 = fmaxf(p0 + b1_0, 0.0f);
    float hh1 = fmaxf(p1 + b1_1, 0.0f);
    float a0 = 0.0f, a1 = 0.0f;
#pragma unroll
    for (int c = 0; c < NC; ++c) {
      float xc = lane_bcast(xd, c);  // xdot is wave-uniform -> SGPR
      float gA = tanh_fast(fmaf(w2a[c], hh0, fmaf(w2b[c], hh1, b2r[c])));
      float gB = tanh_fast(fmaf(w2a[16 + c], hh0, fmaf(w2b[16 + c], hh1, b2r[16 + c])));
      a0 = fmaf(gA, xc, a0);
      a1 = fmaf(gB, xc, a1);
    }
    k0 = a0;
    k1 = a1;
  };

  store_out(0, za, zb);

  const int cl = lane & 15;
#pragma unroll 1
  for (int s = 0; s < NL - 1; ++s) {
    float vrow = crow[s * 64 + lane];
    // gather this lane's c-component of sb/sc/sd (lane holds index cl)
    float vb = __shfl(vrow, 16 + cl, 64);
    float vc = __shfl(vrow, 32 + cl, 64);
    float vd = __shfl(vrow, 48 + cl, 64);
    float xd0 = vb;
    float xdh = fmaf(0.25f, vd, fmaf(0.5f, vc, vb));
    float xd1 = vb + (vc + vd);

    float k10, k11, k20, k21, k30, k31, k40, k41;
    vf(za, zb, xd0, k10, k11);
    vf(fmaf(0.5f, k10, za), fmaf(0.5f, k11, zb), xdh, k20, k21);
    vf(fmaf(0.5f, k20, za), fmaf(0.5f, k21, zb), xdh, k30, k31);
    vf(za + k30, zb + k31, xd1, k40, k41);

    za += (k10 + 2.0f * (k20 + k30) + k40) * (1.0f / 6.0f);
    zb += (k11 + 2.0f * (k21 + k31) + k41) * (1.0f / 6.0f);

    store_out(s + 1, za, zb);
  }
}

extern "C" void kernel_launch(void* const* d_in, const int* in_sizes, int n_in,
                              void* d_out, int out_size, void* d_ws, size_t ws_size,
                              hipStream_t stream) {
  const float* coeffs = (const float*)d_in[0];
  const float* W_init = (const float*)d_in[1];
  const float* b_init = (const float*)d_in[2];
  const float* W1     = (const float*)d_in[3];
  const float* b1     = (const float*)d_in[4];
  const float* W2     = (const float*)d_in[5];
  const float* b2     = (const float*)d_in[6];
  const float* W_out  = (const float*)d_in[7];
  const float* b_out  = (const float*)d_in[8];
  float* out = (float*)d_out;

  // 4 waves (= 4 batch elements) per 256-thread block
  ncde_kernel<<<NB / 4, 256, 0, stream>>>(coeffs, W_init, b_init, W1, b1, W2,
                                          b2, W_out, b_out, out);
}

// Round 2
// 2480.199 us; speedup vs baseline: 1.1188x; 1.1188x over previous
//
#include <hip/hip_runtime.h>

// (B, L, C, H, O) = (4096, 256, 16, 128, 4)
#define NB 4096
#define NL 256
#define NC 16
#define NH 128
#define NO 4

__device__ __forceinline__ float lane_bcast(float v, int l) {
  return __uint_as_float(__builtin_amdgcn_readlane(__float_as_uint(v), l));
}

__device__ __forceinline__ float fast_exp2(float x) {
#if __has_builtin(__builtin_amdgcn_exp2f)
  return __builtin_amdgcn_exp2f(x);
#else
  return exp2f(x);
#endif
}

__device__ __forceinline__ float fast_rcp(float x) {
#if __has_builtin(__builtin_amdgcn_rcpf)
  return __builtin_amdgcn_rcpf(x);
#else
  return 1.0f / x;
#endif
}

// vf(z, xdot):  h = relu(z@W1+b1); g = tanh(h@W2+b2); k = g . xdot
// Weights pre-scaled by 2*log2(e) so tanh(x) = 1 - 2/(exp2(sx)+1) needs no mul.
// k = sum_c xc*(1-2*r_c) = SX - 2 * sum_c xc*r_c   (SX = sum_c xc, per-lane VGPR,
// identical across lanes after the group butterfly).
#define VF(ZSA, ZSB, XDV, SXV, K0, K1)                                        \
  {                                                                           \
    float zsa_ = (ZSA), zsb_ = (ZSB);                                         \
    float p0 = fmaf(zsa_, w1A0, zsb_ * w1B0);                                 \
    float p1 = fmaf(zsa_, w1A1, zsb_ * w1B1);                                 \
    _Pragma("unroll") for (int m_ = 32; m_ >= 1; m_ >>= 1) {                  \
      p0 += __shfl_xor(p0, m_, 64);                                           \
      p1 += __shfl_xor(p1, m_, 64);                                           \
    }                                                                         \
    float hh0 = fmaxf(p0 + b1_0, 0.0f);                                       \
    float hh1 = fmaxf(p1 + b1_1, 0.0f);                                       \
    float accA = 0.0f, accB = 0.0f;                                           \
    _Pragma("unroll") for (int c_ = 0; c_ < NC; ++c_) {                       \
      float xc = lane_bcast((XDV), c_);                                       \
      float eA = fast_exp2(fmaf(w2aA[c_], hh0, fmaf(w2bA[c_], hh1, b2A[c_])));\
      float eB = fast_exp2(fmaf(w2aB[c_], hh0, fmaf(w2bB[c_], hh1, b2B[c_])));\
      accA = fmaf(xc, fast_rcp(eA + 1.0f), accA);                             \
      accB = fmaf(xc, fast_rcp(eB + 1.0f), accB);                             \
    }                                                                         \
    (K0) = fmaf(-2.0f, accA, (SXV));                                          \
    (K1) = fmaf(-2.0f, accB, (SXV));                                          \
  }

#define STORE_OUT(T, ZA_, ZB_)                                                \
  {                                                                           \
    float q0 = fmaf((ZA_), woA0, (ZB_) * woB0);                               \
    float q1 = fmaf((ZA_), woA1, (ZB_) * woB1);                               \
    float q2 = fmaf((ZA_), woA2, (ZB_) * woB2);                               \
    float q3 = fmaf((ZA_), woA3, (ZB_) * woB3);                               \
    _Pragma("unroll") for (int m_ = 32; m_ >= 1; m_ >>= 1) {                  \
      q0 += __shfl_xor(q0, m_, 64);                                           \
      q1 += __shfl_xor(q1, m_, 64);                                           \
      q2 += __shfl_xor(q2, m_, 64);                                           \
      q3 += __shfl_xor(q3, m_, 64);                                           \
    }                                                                         \
    if (lane == 0) {                                                          \
      float4 r_;                                                              \
      r_.x = q0 + bo0; r_.y = q1 + bo1; r_.z = q2 + bo2; r_.w = q3 + bo3;     \
      *(float4*)(obase + (size_t)(T)*NO) = r_;                                \
    }                                                                         \
  }

__global__ __launch_bounds__(256, 2) void ncde_kernel(
    const float* __restrict__ coeffs,  // (B, L-1, 4*C)
    const float* __restrict__ W_init,  // (C, H)
    const float* __restrict__ b_init,  // (H,)
    const float* __restrict__ W1,      // (H, 2)
    const float* __restrict__ b1,      // (2,)
    const float* __restrict__ W2,      // (2, H*C)
    const float* __restrict__ b2,      // (H*C,)
    const float* __restrict__ W_out,   // (H, O)
    const float* __restrict__ b_out,   // (O,)
    float* __restrict__ out)           // (B, L, O)
{
  const int lane = threadIdx.x & 63;
  const int wid  = threadIdx.x >> 6;
  const int bat  = blockIdx.x * 4 + wid;  // one wave per batch element
  const int hA = lane;
  const int hB = lane + 64;
  const float SC = 2.885390081777927f;  // 2*log2(e)

  // ---- loop-invariant weights, register-resident (plain arrays, constant
  // indices after unroll -> SROA; no lambdas anywhere in this kernel) ----
  float w2aA[NC], w2aB[NC], w2bA[NC], w2bB[NC], b2A[NC], b2B[NC];
#pragma unroll
  for (int c = 0; c < NC; ++c) {
    w2aA[c] = W2[hA * NC + c] * SC;
    w2aB[c] = W2[hB * NC + c] * SC;
    w2bA[c] = W2[NH * NC + hA * NC + c] * SC;
    w2bB[c] = W2[NH * NC + hB * NC + c] * SC;
    b2A[c]  = b2[hA * NC + c] * SC;
    b2B[c]  = b2[hB * NC + c] * SC;
  }
  const float w1A0 = W1[hA * 2 + 0], w1A1 = W1[hA * 2 + 1];
  const float w1B0 = W1[hB * 2 + 0], w1B1 = W1[hB * 2 + 1];
  const float woA0 = W_out[hA * NO + 0], woA1 = W_out[hA * NO + 1];
  const float woA2 = W_out[hA * NO + 2], woA3 = W_out[hA * NO + 3];
  const float woB0 = W_out[hB * NO + 0], woB1 = W_out[hB * NO + 1];
  const float woB2 = W_out[hB * NO + 2], woB3 = W_out[hB * NO + 3];
  const float bo0 = b_out[0], bo1 = b_out[1], bo2 = b_out[2], bo3 = b_out[3];
  const float b1_0 = b1[0], b1_1 = b1[1];

  const float* crow = coeffs + (size_t)bat * (NL - 1) * (4 * NC);
  float* obase = out + (size_t)bat * NL * NO;

  // ---- z0 = X0 @ W_init + b_init ----
  float v0 = crow[lane];
  float za = b_init[hA], zb = b_init[hB];
#pragma unroll
  for (int c = 0; c < NC; ++c) {
    float xc = lane_bcast(v0, c);
    za = fmaf(xc, W_init[c * NH + hA], za);
    zb = fmaf(xc, W_init[c * NH + hB], zb);
  }

  STORE_OUT(0, za, zb);

  const int cl = lane & 15;
#pragma unroll 1
  for (int s = 0; s < NL - 1; ++s) {
    float vrow = crow[s * 64 + lane];
    float vb = __shfl(vrow, 16 + cl, 64);
    float vc = __shfl(vrow, 32 + cl, 64);
    float vd = __shfl(vrow, 48 + cl, 64);
    float xd0 = vb;
    float xdh = fmaf(0.25f, vd, fmaf(0.5f, vc, vb));
    float xd1 = vb + (vc + vd);

    // per-xdot component sums over the 16-group (wave-uniform result)
    float sx0 = xd0, sxh = xdh, sx1 = xd1;
#pragma unroll
    for (int m = 8; m >= 1; m >>= 1) {
      sx0 += __shfl_xor(sx0, m, 64);
      sxh += __shfl_xor(sxh, m, 64);
      sx1 += __shfl_xor(sx1, m, 64);
    }

    float k10, k11, k20, k21, k30, k31, k40, k41;
    VF(za, zb, xd0, sx0, k10, k11);
    VF(fmaf(0.5f, k10, za), fmaf(0.5f, k11, zb), xdh, sxh, k20, k21);
    VF(fmaf(0.5f, k20, za), fmaf(0.5f, k21, zb), xdh, sxh, k30, k31);
    VF(za + k30, zb + k31, xd1, sx1, k40, k41);

    za += (k10 + 2.0f * (k20 + k30) + k40) * (1.0f / 6.0f);
    zb += (k11 + 2.0f * (k21 + k31) + k41) * (1.0f / 6.0f);

    STORE_OUT(s + 1, za, zb);
  }
}

extern "C" void kernel_launch(void* const* d_in, const int* in_sizes, int n_in,
                              void* d_out, int out_size, void* d_ws, size_t ws_size,
                              hipStream_t stream) {
  const float* coeffs = (const float*)d_in[0];
  const float* W_init = (const float*)d_in[1];
  const float* b_init = (const float*)d_in[2];
  const float* W1     = (const float*)d_in[3];
  const float* b1     = (const float*)d_in[4];
  const float* W2     = (const float*)d_in[5];
  const float* b2     = (const float*)d_in[6];
  const float* W_out  = (const float*)d_in[7];
  const float* b_out  = (const float*)d_in[8];
  float* out = (float*)d_out;

  ncde_kernel<<<NB / 4, 256, 0, stream>>>(coeffs, W_init, b_init, W1, b1, W2,
                                          b2, W_out, b_out, out);
}